// Round 1
// baseline (13703.107 us; speedup 1.0000x reference)
//
#include <hip/hip_runtime.h>

typedef __attribute__((ext_vector_type(8))) short bf16x8;
typedef __attribute__((ext_vector_type(4))) float f32x4;

#define MFMA16(a,b,c) __builtin_amdgcn_mfma_f32_16x16x32_bf16((a),(b),(c),0,0,0)

// ---------------- sizes ----------------
// B=256 T=512 D=32 H=256 4H=1024

// ---------------- ws layout (bytes) ----------------
#define SZ_HBUF   (2*256*256*2)              // one h array: [2 parity][256 b][256 u] bf16
#define OFF_H0H   0
#define OFF_H0L   (OFF_H0H + SZ_HBUF)
#define OFF_H1H   (OFF_H0L + SZ_HBUF)
#define OFF_H1L   (OFF_H1H + SZ_HBUF)
#define OFF_CFIN  (OFF_H1L + SZ_HBUF)        // [2 layer][256][256] f32 = 524288
#define OFF_EW0H  (OFF_CFIN + 524288)        // enc L0 cat [1024][288] bf16 = 589824
#define OFF_EW0L  (OFF_EW0H + 589824)
#define OFF_EW1H  (OFF_EW0L + 589824)        // enc L1 cat [1024][512] bf16 = 1048576
#define OFF_EW1L  (OFF_EW1H + 1048576)
#define OFF_DW0H  (OFF_EW1L + 1048576)       // dec L0 cat [Weff|Whh0] [1024][512]
#define OFF_DW0L  (OFF_DW0H + 1048576)
#define OFF_DW1H  (OFF_DW0L + 1048576)       // dec L1 cat [Wih1|Whh1]
#define OFF_DW1L  (OFF_DW1H + 1048576)
#define OFF_BEFF  (OFF_DW1L + 1048576)       // 1024 f32
#define OFF_CTR   (OFF_BEFF + 4096)          // enc ctr 1024B, dec ctr 1024B

// ---------------- helpers ----------------
static __device__ __forceinline__ unsigned short f2bf(float f) {
  unsigned u = __float_as_uint(f);
  u = u + 0x7fffu + ((u >> 16) & 1u);
  return (unsigned short)(u >> 16);
}
static __device__ __forceinline__ float bf2f(unsigned short s) {
  return __uint_as_float(((unsigned)s) << 16);
}
static __device__ __forceinline__ float sigf(float x) {
  return 1.f / (1.f + __expf(-x));
}
static __device__ __forceinline__ float tanhsafe(float x) {
  float a = fabsf(x);
  float e = __expf(-2.f * a);          // e in (0,1], never overflows
  float t = (1.f - e) / (1.f + e);
  return x < 0.f ? -t : t;
}
// coherent (agent-scope, LLC) 16B fragment load: two relaxed 8B atomic loads
static __device__ __forceinline__ bf16x8 ld_frag(const unsigned short* p) {
  union { bf16x8 v; unsigned long long q[2]; } u;
  u.q[0] = __hip_atomic_load((const unsigned long long*)p,     __ATOMIC_RELAXED, __HIP_MEMORY_SCOPE_AGENT);
  u.q[1] = __hip_atomic_load((const unsigned long long*)p + 1, __ATOMIC_RELAXED, __HIP_MEMORY_SCOPE_AGENT);
  return u.v;
}
// split h into bf16 hi+lo and store coherently (agent scope)
static __device__ __forceinline__ void st_hpair(float h, unsigned short* ph, unsigned short* pl) {
  unsigned short hi = f2bf(h);
  unsigned short lo = f2bf(h - bf2f(hi));
  __hip_atomic_store(ph, hi, __ATOMIC_RELAXED, __HIP_MEMORY_SCOPE_AGENT);
  __hip_atomic_store(pl, lo, __ATOMIC_RELAXED, __HIP_MEMORY_SCOPE_AGENT);
}
// barrier among the 16 WGs of one batch-group. Monotonic target.
// __syncthreads() drains each wave's outstanding (sc-flagged, LLC-visible) stores first.
static __device__ __forceinline__ void group_barrier(unsigned* ctr, unsigned target) {
  __syncthreads();
  if (threadIdx.x == 0) {
    __hip_atomic_fetch_add(ctr, 1u, __ATOMIC_RELAXED, __HIP_MEMORY_SCOPE_AGENT);
    while (__hip_atomic_load(ctr, __ATOMIC_RELAXED, __HIP_MEMORY_SCOPE_AGENT) < target)
      __builtin_amdgcn_s_sleep(1);
  }
  __syncthreads();
}

// ---------------- prep kernels ----------------
__global__ void k_prep_cat(const float* __restrict__ s0, int K0,
                           const float* __restrict__ s1, int K1,
                           unsigned short* __restrict__ whi, unsigned short* __restrict__ wlo) {
  int K = K0 + K1;
  int tot = 1024 * K;
  for (int idx = blockIdx.x * blockDim.x + threadIdx.x; idx < tot; idx += gridDim.x * blockDim.x) {
    int n = idx / K, k = idx - n * K;
    float v = (k < K0) ? s0[n * K0 + k] : s1[n * K1 + (k - K0)];
    unsigned short hi = f2bf(v);
    unsigned short lo = f2bf(v - bf2f(hi));
    whi[idx] = hi; wlo[idx] = lo;
  }
}
// dec L0 cat: cols 0..255 = Weff = Wih0 @ fcW, cols 256..511 = Whh0
__global__ void k_prep_dec0(const float* __restrict__ Wih0, const float* __restrict__ Whh0,
                            const float* __restrict__ fcW,
                            unsigned short* __restrict__ whi, unsigned short* __restrict__ wlo) {
  int tot = 1024 * 512;
  for (int idx = blockIdx.x * blockDim.x + threadIdx.x; idx < tot; idx += gridDim.x * blockDim.x) {
    int n = idx >> 9, k = idx & 511;
    float v;
    if (k < 256) {
      v = 0.f;
      #pragma unroll
      for (int d = 0; d < 32; ++d) v += Wih0[n * 32 + d] * fcW[d * 256 + k];
    } else {
      v = Whh0[n * 256 + (k - 256)];
    }
    unsigned short hi = f2bf(v);
    unsigned short lo = f2bf(v - bf2f(hi));
    whi[idx] = hi; wlo[idx] = lo;
  }
}
__global__ void k_prep_beff(const float* __restrict__ Wih0, const float* __restrict__ b0,
                            const float* __restrict__ fcb, float* __restrict__ beff) {
  int n = blockIdx.x * blockDim.x + threadIdx.x;
  if (n < 1024) {
    float v = b0[n];
    #pragma unroll
    for (int d = 0; d < 32; ++d) v += Wih0[n * 32 + d] * fcb[d];
    beff[n] = v;
  }
}

// ---------------- encoder ----------------
// grid 256 WGs x 256 thr. gb = wg&15 (batch group: rows gb*16..+15), gc = wg>>4 (units gc*16..+15).
// wave wid = gate (i,f,g,o). Layer1 runs 1 step behind layer0 -> 1 group barrier / iteration.
__global__ __launch_bounds__(256, 1)
void k_encoder(const float* __restrict__ input,
               const unsigned short* __restrict__ w0hi, const unsigned short* __restrict__ w0lo,
               const unsigned short* __restrict__ w1hi, const unsigned short* __restrict__ w1lo,
               const float* __restrict__ b0, const float* __restrict__ b1,
               unsigned short* h0h, unsigned short* h0l,
               unsigned short* h1h, unsigned short* h1l,
               float* __restrict__ cfin, unsigned* ctr)
{
  const int wg = blockIdx.x;
  const int gb = wg & 15, gc = wg >> 4;
  const int tid = threadIdx.x;
  const int wid = tid >> 6, lane = tid & 63;
  const int lcol = lane & 15, lrow = lane >> 4;
  const int r0 = gb * 16, u0 = gc * 16;
  const int wrow = wid * 256 + u0 + lcol;

  __shared__ float gA[4][16][17];
  __shared__ float gB[4][16][17];
  __shared__ float cb[2][16][16];

  cb[0][tid >> 4][tid & 15] = 0.f;
  cb[1][tid >> 4][tid & 15] = 0.f;

  // weight fragments resident in VGPRs (bf16 hi+lo)
  bf16x8 w0h_[9], w0l_[9], w1h_[16], w1l_[16];
  {
    const unsigned short* p = w0hi + (size_t)wrow * 288 + lrow * 8;
    const unsigned short* q = w0lo + (size_t)wrow * 288 + lrow * 8;
    #pragma unroll
    for (int kk = 0; kk < 9; ++kk) {
      w0h_[kk] = *(const bf16x8*)(p + kk * 32);
      w0l_[kk] = *(const bf16x8*)(q + kk * 32);
    }
    const unsigned short* p1 = w1hi + (size_t)wrow * 512 + lrow * 8;
    const unsigned short* q1 = w1lo + (size_t)wrow * 512 + lrow * 8;
    #pragma unroll
    for (int kk = 0; kk < 16; ++kk) {
      w1h_[kk] = *(const bf16x8*)(p1 + kk * 32);
      w1l_[kk] = *(const bf16x8*)(q1 + kk * 32);
    }
  }
  const float bias0 = b0[wrow];
  const float bias1 = b1[wrow];
  const int arow = r0 + lcol;
  unsigned* myctr = ctr + gb * 16;
  unsigned tgt = 16;
  __syncthreads();

  for (int k = 0; k <= 512; ++k) {
    const int rp = (k - 1) & 1;   // h0 read parity (h0(k-1)); also h1 write parity
    const int wp = k & 1;         // h0 write parity; h1 read parity (h1(k-2))

    // shared A fragments: h0(k-1) feeds BOTH L0 (recurrent) and L1 (sequence input)
    bf16x8 f0h[8], f0l[8], f1h[8], f1l[8];
    {
      const unsigned short* bh = h0h + (size_t)rp * 65536 + (size_t)arow * 256 + lrow * 8;
      const unsigned short* bl = h0l + (size_t)rp * 65536 + (size_t)arow * 256 + lrow * 8;
      #pragma unroll
      for (int kk = 0; kk < 8; ++kk) { f0h[kk] = ld_frag(bh + kk * 32); f0l[kk] = ld_frag(bl + kk * 32); }
      const unsigned short* ch = h1h + (size_t)wp * 65536 + (size_t)arow * 256 + lrow * 8;
      const unsigned short* cl = h1l + (size_t)wp * 65536 + (size_t)arow * 256 + lrow * 8;
      #pragma unroll
      for (int kk = 0; kk < 8; ++kk) { f1h[kk] = ld_frag(ch + kk * 32); f1l[kk] = ld_frag(cl + kk * 32); }
    }

    if (k < 512) {  // ---- layer0 step k : gates = x_k @ Wih0^T + h0 @ Whh0^T
      union { bf16x8 v; unsigned short s[8]; } xh, xl;
      {
        const float* px = input + (size_t)arow * 16384 + (size_t)k * 32 + lrow * 8;
        f32x4 a = *(const f32x4*)px;
        f32x4 b = *(const f32x4*)(px + 4);
        #pragma unroll
        for (int j = 0; j < 4; ++j) {
          unsigned short t1 = f2bf(a[j]); xh.s[j] = t1;     xl.s[j]     = f2bf(a[j] - bf2f(t1));
          unsigned short t2 = f2bf(b[j]); xh.s[4 + j] = t2; xl.s[4 + j] = f2bf(b[j] - bf2f(t2));
        }
      }
      f32x4 ahh = {0.f,0.f,0.f,0.f}, ahl = {0.f,0.f,0.f,0.f}, alh = {0.f,0.f,0.f,0.f};
      ahh = MFMA16(xh.v, w0h_[0], ahh);
      ahl = MFMA16(xh.v, w0l_[0], ahl);
      alh = MFMA16(xl.v, w0h_[0], alh);
      #pragma unroll
      for (int kk = 0; kk < 8; ++kk) {
        ahh = MFMA16(f0h[kk], w0h_[kk + 1], ahh);
        ahl = MFMA16(f0h[kk], w0l_[kk + 1], ahl);
        alh = MFMA16(f0l[kk], w0h_[kk + 1], alh);
      }
      f32x4 g = ahh + ahl + alh;
      #pragma unroll
      for (int r = 0; r < 4; ++r) gA[wid][lrow * 4 + r][lcol] = g[r] + bias0;
    }
    if (k >= 1) {   // ---- layer1 step k-1 : A = [h0(k-1) | h1(k-2)]
      f32x4 ahh = {0.f,0.f,0.f,0.f}, ahl = {0.f,0.f,0.f,0.f}, alh = {0.f,0.f,0.f,0.f};
      #pragma unroll
      for (int kk = 0; kk < 8; ++kk) {
        ahh = MFMA16(f0h[kk], w1h_[kk], ahh);
        ahl = MFMA16(f0h[kk], w1l_[kk], ahl);
        alh = MFMA16(f0l[kk], w1h_[kk], alh);
      }
      #pragma unroll
      for (int kk = 0; kk < 8; ++kk) {
        ahh = MFMA16(f1h[kk], w1h_[kk + 8], ahh);
        ahl = MFMA16(f1h[kk], w1l_[kk + 8], ahl);
        alh = MFMA16(f1l[kk], w1h_[kk + 8], alh);
      }
      f32x4 g = ahh + ahl + alh;
      #pragma unroll
      for (int r = 0; r < 4; ++r) gB[wid][lrow * 4 + r][lcol] = g[r] + bias1;
    }
    __syncthreads();

    const int urow = tid >> 4, uu = tid & 15;
    if (k < 512) {
      float gi = gA[0][urow][uu], gf = gA[1][urow][uu];
      float gg = gA[2][urow][uu], go = gA[3][urow][uu];
      float c = sigf(gf) * cb[0][urow][uu] + sigf(gi) * tanhsafe(gg);
      cb[0][urow][uu] = c;
      float h = sigf(go) * tanhsafe(c);
      size_t off = (size_t)wp * 65536 + (size_t)(r0 + urow) * 256 + (u0 + uu);
      st_hpair(h, h0h + off, h0l + off);
    }
    if (k >= 1) {
      float gi = gB[0][urow][uu], gf = gB[1][urow][uu];
      float gg = gB[2][urow][uu], go = gB[3][urow][uu];
      float c = sigf(gf) * cb[1][urow][uu] + sigf(gi) * tanhsafe(gg);
      cb[1][urow][uu] = c;
      float h = sigf(go) * tanhsafe(c);
      size_t off = (size_t)rp * 65536 + (size_t)(r0 + urow) * 256 + (u0 + uu);
      st_hpair(h, h1h + off, h1l + off);
    }
    group_barrier(myctr, tgt);
    tgt += 16;
  }

  // final cell states -> global (decoder initial state). Final h already in parity-1 slices.
  const int urow = tid >> 4, uu = tid & 15;
  cfin[(size_t)(r0 + urow) * 256 + (u0 + uu)] = cb[0][urow][uu];
  cfin[65536 + (size_t)(r0 + urow) * 256 + (u0 + uu)] = cb[1][urow][uu];
}

// ---------------- decoder ----------------
// L0 gates = h1 @ Weff^T + h0 @ Whh0^T + beff   (x-feedback folded via Weff = Wih0@fcW)
// L1 gates = h0' @ Wih1^T + h1 @ Whh1^T + b1
// pred_t = h1' @ fcW^T + fc_b  (per-WG 16-unit partial, atomicAdd, written reversed in time)
__global__ __launch_bounds__(256, 1)
void k_decoder(const unsigned short* __restrict__ w0hi, const unsigned short* __restrict__ w0lo,
               const unsigned short* __restrict__ w1hi, const unsigned short* __restrict__ w1lo,
               const float* __restrict__ beff, const float* __restrict__ db0,
               const float* __restrict__ b1,
               const float* __restrict__ fcW, const float* __restrict__ fcb,
               unsigned short* h0h, unsigned short* h0l,
               unsigned short* h1h, unsigned short* h1l,
               const float* __restrict__ cfin, float* out, unsigned* ctr)
{
  const int wg = blockIdx.x;
  const int gb = wg & 15, gc = wg >> 4;
  const int tid = threadIdx.x;
  const int wid = tid >> 6, lane = tid & 63;
  const int lcol = lane & 15, lrow = lane >> 4;
  const int r0 = gb * 16, u0 = gc * 16;
  const int wrow = wid * 256 + u0 + lcol;

  __shared__ float gA[4][16][17];
  __shared__ float cb[2][16][16];
  __shared__ float hp[16][17];
  __shared__ float fw[32][17];

  {
    const int urow = tid >> 4, uu = tid & 15;
    cb[0][urow][uu] = cfin[(size_t)(r0 + urow) * 256 + (u0 + uu)];
    cb[1][urow][uu] = cfin[65536 + (size_t)(r0 + urow) * 256 + (u0 + uu)];
  }
  for (int o = tid; o < 512; o += 256) {
    int col = o >> 4, u = o & 15;
    fw[col][u] = fcW[(size_t)col * 256 + (u0 + u)];
  }

  bf16x8 w0h_[16], w0l_[16], w1h_[16], w1l_[16];
  {
    const unsigned short* p = w0hi + (size_t)wrow * 512 + lrow * 8;
    const unsigned short* q = w0lo + (size_t)wrow * 512 + lrow * 8;
    #pragma unroll
    for (int kk = 0; kk < 16; ++kk) {
      w0h_[kk] = *(const bf16x8*)(p + kk * 32);
      w0l_[kk] = *(const bf16x8*)(q + kk * 32);
    }
    const unsigned short* p1 = w1hi + (size_t)wrow * 512 + lrow * 8;
    const unsigned short* q1 = w1lo + (size_t)wrow * 512 + lrow * 8;
    #pragma unroll
    for (int kk = 0; kk < 16; ++kk) {
      w1h_[kk] = *(const bf16x8*)(p1 + kk * 32);
      w1l_[kk] = *(const bf16x8*)(q1 + kk * 32);
    }
  }
  const float bias0 = beff[wrow], bias0t0 = db0[wrow], bias1 = b1[wrow];
  const int arow = r0 + lcol;
  unsigned* myctr = ctr + gb * 16;
  unsigned tgt = 16;
  __syncthreads();

  for (int t = 0; t < 512; ++t) {
    const int wp = t & 1, rp = 1 - wp;

    // ================= phase A : layer0 =================
    {
      bf16x8 fh[16], fl[16];
      const unsigned short* ah = h1h + (size_t)rp * 65536 + (size_t)arow * 256 + lrow * 8;
      const unsigned short* al = h1l + (size_t)rp * 65536 + (size_t)arow * 256 + lrow * 8;
      #pragma unroll
      for (int kk = 0; kk < 8; ++kk) { fh[kk] = ld_frag(ah + kk * 32); fl[kk] = ld_frag(al + kk * 32); }
      const unsigned short* bh = h0h + (size_t)rp * 65536 + (size_t)arow * 256 + lrow * 8;
      const unsigned short* bl = h0l + (size_t)rp * 65536 + (size_t)arow * 256 + lrow * 8;
      #pragma unroll
      for (int kk = 0; kk < 8; ++kk) { fh[8 + kk] = ld_frag(bh + kk * 32); fl[8 + kk] = ld_frag(bl + kk * 32); }

      f32x4 ahh = {0.f,0.f,0.f,0.f}, ahl = {0.f,0.f,0.f,0.f}, alh = {0.f,0.f,0.f,0.f};
      if (t > 0) {  // t==0: x = 0, no h1/Weff contribution, plain b0 bias
        #pragma unroll
        for (int kk = 0; kk < 8; ++kk) {
          ahh = MFMA16(fh[kk], w0h_[kk], ahh);
          ahl = MFMA16(fh[kk], w0l_[kk], ahl);
          alh = MFMA16(fl[kk], w0h_[kk], alh);
        }
      }
      #pragma unroll
      for (int kk = 8; kk < 16; ++kk) {
        ahh = MFMA16(fh[kk], w0h_[kk], ahh);
        ahl = MFMA16(fh[kk], w0l_[kk], ahl);
        alh = MFMA16(fl[kk], w0h_[kk], alh);
      }
      f32x4 g = ahh + ahl + alh;
      float bb = (t == 0) ? bias0t0 : bias0;
      #pragma unroll
      for (int r = 0; r < 4; ++r) gA[wid][lrow * 4 + r][lcol] = g[r] + bb;
    }
    __syncthreads();
    {
      const int urow = tid >> 4, uu = tid & 15;
      float gi = gA[0][urow][uu], gf = gA[1][urow][uu];
      float gg = gA[2][urow][uu], go = gA[3][urow][uu];
      float c = sigf(gf) * cb[0][urow][uu] + sigf(gi) * tanhsafe(gg);
      cb[0][urow][uu] = c;
      float h = sigf(go) * tanhsafe(c);
      size_t off = (size_t)wp * 65536 + (size_t)(r0 + urow) * 256 + (u0 + uu);
      st_hpair(h, h0h + off, h0l + off);
    }
    group_barrier(myctr, tgt); tgt += 16;

    // ================= phase B : layer1 + fc =================
    {
      bf16x8 fh[16], fl[16];
      const unsigned short* ah = h0h + (size_t)wp * 65536 + (size_t)arow * 256 + lrow * 8;  // new h0
      const unsigned short* al = h0l + (size_t)wp * 65536 + (size_t)arow * 256 + lrow * 8;
      #pragma unroll
      for (int kk = 0; kk < 8; ++kk) { fh[kk] = ld_frag(ah + kk * 32); fl[kk] = ld_frag(al + kk * 32); }
      const unsigned short* bh = h1h + (size_t)rp * 65536 + (size_t)arow * 256 + lrow * 8;  // old h1
      const unsigned short* bl = h1l + (size_t)rp * 65536 + (size_t)arow * 256 + lrow * 8;
      #pragma unroll
      for (int kk = 0; kk < 8; ++kk) { fh[8 + kk] = ld_frag(bh + kk * 32); fl[8 + kk] = ld_frag(bl + kk * 32); }

      f32x4 ahh = {0.f,0.f,0.f,0.f}, ahl = {0.f,0.f,0.f,0.f}, alh = {0.f,0.f,0.f,0.f};
      #pragma unroll
      for (int kk = 0; kk < 16; ++kk) {
        ahh = MFMA16(fh[kk], w1h_[kk], ahh);
        ahl = MFMA16(fh[kk], w1l_[kk], ahl);
        alh = MFMA16(fl[kk], w1h_[kk], alh);
      }
      f32x4 g = ahh + ahl + alh;
      #pragma unroll
      for (int r = 0; r < 4; ++r) gA[wid][lrow * 4 + r][lcol] = g[r] + bias1;
    }
    __syncthreads();
    {
      const int urow = tid >> 4, uu = tid & 15;
      float gi = gA[0][urow][uu], gf = gA[1][urow][uu];
      float gg = gA[2][urow][uu], go = gA[3][urow][uu];
      float c = sigf(gf) * cb[1][urow][uu] + sigf(gi) * tanhsafe(gg);
      cb[1][urow][uu] = c;
      float h = sigf(go) * tanhsafe(c);
      hp[urow][uu] = h;  // fp32 h1' for fc
      size_t off = (size_t)wp * 65536 + (size_t)(r0 + urow) * 256 + (u0 + uu);
      st_hpair(h, h1h + off, h1l + off);
    }
    __syncthreads();
    {
      // fc partial over this WG's 16 units; output written time-reversed
      for (int o = tid; o < 512; o += 256) {
        int row = o >> 5, col = o & 31;
        float s = 0.f;
        #pragma unroll
        for (int u = 0; u < 16; ++u) s += hp[row][u] * fw[col][u];
        if (gc == 0) s += fcb[col];
        atomicAdd(out + (size_t)(r0 + row) * 16384 + (size_t)(511 - t) * 32 + col, s);
      }
    }
    group_barrier(myctr, tgt); tgt += 16;
  }
}

// ---------------- launch ----------------
extern "C" void kernel_launch(void* const* d_in, const int* in_sizes, int n_in,
                              void* d_out, int out_size, void* d_ws, size_t ws_size,
                              hipStream_t stream) {
  (void)in_sizes; (void)n_in; (void)ws_size;
  const float* input = (const float*)d_in[0];
  const float* eWih0 = (const float*)d_in[1];
  const float* eWhh0 = (const float*)d_in[2];
  const float* eb0   = (const float*)d_in[3];
  const float* eWih1 = (const float*)d_in[4];
  const float* eWhh1 = (const float*)d_in[5];
  const float* eb1   = (const float*)d_in[6];
  const float* dWih0 = (const float*)d_in[7];
  const float* dWhh0 = (const float*)d_in[8];
  const float* db0   = (const float*)d_in[9];
  const float* dWih1 = (const float*)d_in[10];
  const float* dWhh1 = (const float*)d_in[11];
  const float* db1   = (const float*)d_in[12];
  const float* fcW   = (const float*)d_in[13];
  const float* fcb   = (const float*)d_in[14];

  char* ws = (char*)d_ws;
  unsigned short* h0h = (unsigned short*)(ws + OFF_H0H);
  unsigned short* h0l = (unsigned short*)(ws + OFF_H0L);
  unsigned short* h1h = (unsigned short*)(ws + OFF_H1H);
  unsigned short* h1l = (unsigned short*)(ws + OFF_H1L);
  float* cfin = (float*)(ws + OFF_CFIN);
  unsigned short* ew0h = (unsigned short*)(ws + OFF_EW0H);
  unsigned short* ew0l = (unsigned short*)(ws + OFF_EW0L);
  unsigned short* ew1h = (unsigned short*)(ws + OFF_EW1H);
  unsigned short* ew1l = (unsigned short*)(ws + OFF_EW1L);
  unsigned short* dw0h = (unsigned short*)(ws + OFF_DW0H);
  unsigned short* dw0l = (unsigned short*)(ws + OFF_DW0L);
  unsigned short* dw1h = (unsigned short*)(ws + OFF_DW1H);
  unsigned short* dw1l = (unsigned short*)(ws + OFF_DW1L);
  float* beff = (float*)(ws + OFF_BEFF);
  unsigned* ectr = (unsigned*)(ws + OFF_CTR);
  unsigned* dctr = (unsigned*)(ws + OFF_CTR + 1024);

  hipMemsetAsync(d_out, 0, (size_t)out_size * sizeof(float), stream);
  hipMemsetAsync(ws + OFF_H0H, 0, (size_t)4 * SZ_HBUF, stream);   // h buffers (zero initial state)
  hipMemsetAsync(ws + OFF_CTR, 0, 2048, stream);                  // barrier counters

  k_prep_cat<<<1024, 256, 0, stream>>>(eWih0, 32,  eWhh0, 256, ew0h, ew0l);
  k_prep_cat<<<1024, 256, 0, stream>>>(eWih1, 256, eWhh1, 256, ew1h, ew1l);
  k_prep_cat<<<1024, 256, 0, stream>>>(dWih1, 256, dWhh1, 256, dw1h, dw1l);
  k_prep_dec0<<<1024, 256, 0, stream>>>(dWih0, dWhh0, fcW, dw0h, dw0l);
  k_prep_beff<<<4, 256, 0, stream>>>(dWih0, db0, fcb, beff);

  k_encoder<<<256, 256, 0, stream>>>(input, ew0h, ew0l, ew1h, ew1l, eb0, eb1,
                                     h0h, h0l, h1h, h1l, cfin, ectr);
  k_decoder<<<256, 256, 0, stream>>>(dw0h, dw0l, dw1h, dw1l, beff, db0, db1,
                                     fcW, fcb, h0h, h0l, h1h, h1l, cfin, (float*)d_out, dctr);
}

// Round 3
// 8450.688 us; speedup vs baseline: 1.6215x; 1.6215x over previous
//
#include <hip/hip_runtime.h>

typedef __attribute__((ext_vector_type(8))) short bf16x8;
typedef __attribute__((ext_vector_type(4))) float f32x4;

#define MFMA16(a,b,c) __builtin_amdgcn_mfma_f32_16x16x32_bf16((a),(b),(c),0,0,0)

// ---------------- sizes ----------------
// B=256 T=512 D=32 H=256 4H=1024

// ---------------- ws layout (bytes) ----------------
#define SZ_HBUF   (2*256*256*2)              // one h array: [2 parity][256 b][256 u] bf16
#define OFF_H0H   0
#define OFF_H0L   (OFF_H0H + SZ_HBUF)
#define OFF_H1H   (OFF_H0L + SZ_HBUF)
#define OFF_H1L   (OFF_H1H + SZ_HBUF)
#define OFF_CFIN  (OFF_H1L + SZ_HBUF)        // [2 layer][256][256] f32 = 524288
#define OFF_EW0H  (OFF_CFIN + 524288)        // enc L0 cat [1024][288] bf16
#define OFF_EW0L  (OFF_EW0H + 589824)
#define OFF_EW1H  (OFF_EW0L + 589824)        // enc L1 cat [1024][512] bf16
#define OFF_EW1L  (OFF_EW1H + 1048576)
#define OFF_DW0H  (OFF_EW1L + 1048576)       // dec L0 cat [Weff|Whh0] [1024][512]
#define OFF_DW0L  (OFF_DW0H + 1048576)
#define OFF_DW1H  (OFF_DW0L + 1048576)       // dec L1 cat [Wih1|Whh1]
#define OFF_DW1L  (OFF_DW1H + 1048576)
#define OFF_BEFF  (OFF_DW1L + 1048576)       // 1024 f32
#define OFF_FCWH  (OFF_BEFF + 4096)          // fc W [32][256] bf16 hi
#define OFF_FCWL  (OFF_FCWH + 16384)
#define OFF_EFLG  (OFF_FCWL + 16384)         // encoder flags: 16 groups x 64 uints
#define OFF_DFLG  (OFF_EFLG + 4096)          // decoder flags

// ---------------- helpers ----------------
static __device__ __forceinline__ unsigned short f2bf(float f) {
  unsigned u = __float_as_uint(f);
  u = u + 0x7fffu + ((u >> 16) & 1u);
  return (unsigned short)(u >> 16);
}
static __device__ __forceinline__ float bf2f(unsigned short s) {
  return __uint_as_float(((unsigned)s) << 16);
}
static __device__ __forceinline__ float sigf(float x) {
  return 1.f / (1.f + __expf(-x));
}
static __device__ __forceinline__ float tanhsafe(float x) {
  float a = fabsf(x);
  float e = __expf(-2.f * a);
  float t = (1.f - e) / (1.f + e);
  return x < 0.f ? -t : t;
}
// split h into bf16 hi+lo and store coherently (agent scope)
static __device__ __forceinline__ void st_hpair(float h, unsigned short* ph, unsigned short* pl) {
  unsigned short hi = f2bf(h);
  unsigned short lo = f2bf(h - bf2f(hi));
  __hip_atomic_store(ph, hi, __ATOMIC_RELAXED, __HIP_MEMORY_SCOPE_AGENT);
  __hip_atomic_store(pl, lo, __ATOMIC_RELAXED, __HIP_MEMORY_SCOPE_AGENT);
}
static __device__ __forceinline__ unsigned long long ld_coh8(const void* p) {
  return __hip_atomic_load((const unsigned long long*)p, __ATOMIC_RELAXED, __HIP_MEMORY_SCOPE_AGENT);
}
// flag barrier: each WG publishes monotonically-increasing round; wave0 polls 16 flags in one load
static __device__ __forceinline__ void flag_barrier(unsigned* flags, int gc, unsigned round) {
  __syncthreads();                 // all waves drain their agent-visible stores
  if (threadIdx.x == 0)
    __hip_atomic_store(flags + gc, round, __ATOMIC_RELAXED, __HIP_MEMORY_SCOPE_AGENT);
  if (threadIdx.x < 64) {
    int l = threadIdx.x;
    for (;;) {
      unsigned v = (l < 16) ? __hip_atomic_load(flags + l, __ATOMIC_RELAXED, __HIP_MEMORY_SCOPE_AGENT)
                            : round;
      if (__all((int)(v >= round))) break;
    }
  }
  __syncthreads();
}

// swizzled LDS fragment read: 16B at (row*512 | lrow*16 | kk*64) ^ ((row&7)<<4)
#define LDSF(base, row, kk) \
  (*(const bf16x8*)((base) + ((((row) << 9) | (lrow << 4) | ((kk) << 6)) ^ (((row) & 7) << 4))))

// ---------------- prep kernels ----------------
__global__ void k_prep_cat(int nrows, const float* __restrict__ s0, int K0,
                           const float* __restrict__ s1, int K1,
                           unsigned short* __restrict__ whi, unsigned short* __restrict__ wlo) {
  int K = K0 + K1;
  int tot = nrows * K;
  for (int idx = blockIdx.x * blockDim.x + threadIdx.x; idx < tot; idx += gridDim.x * blockDim.x) {
    int n = idx / K, k = idx - n * K;
    float v = (k < K0) ? s0[n * K0 + k] : s1[n * K1 + (k - K0)];
    unsigned short hi = f2bf(v);
    unsigned short lo = f2bf(v - bf2f(hi));
    whi[idx] = hi; wlo[idx] = lo;
  }
}
// dec L0 cat: cols 0..255 = Weff = Wih0 @ fcW, cols 256..511 = Whh0
__global__ void k_prep_dec0(const float* __restrict__ Wih0, const float* __restrict__ Whh0,
                            const float* __restrict__ fcW,
                            unsigned short* __restrict__ whi, unsigned short* __restrict__ wlo) {
  int tot = 1024 * 512;
  for (int idx = blockIdx.x * blockDim.x + threadIdx.x; idx < tot; idx += gridDim.x * blockDim.x) {
    int n = idx >> 9, k = idx & 511;
    float v;
    if (k < 256) {
      v = 0.f;
      #pragma unroll
      for (int d = 0; d < 32; ++d) v += Wih0[n * 32 + d] * fcW[d * 256 + k];
    } else {
      v = Whh0[n * 256 + (k - 256)];
    }
    unsigned short hi = f2bf(v);
    unsigned short lo = f2bf(v - bf2f(hi));
    whi[idx] = hi; wlo[idx] = lo;
  }
}
__global__ void k_prep_beff(const float* __restrict__ Wih0, const float* __restrict__ b0,
                            const float* __restrict__ fcb, float* __restrict__ beff) {
  int n = blockIdx.x * blockDim.x + threadIdx.x;
  if (n < 1024) {
    float v = b0[n];
    #pragma unroll
    for (int d = 0; d < 32; ++d) v += Wih0[n * 32 + d] * fcb[d];
    beff[n] = v;
  }
}

// ---------------- encoder ----------------
// 256 WGs x 256 thr; gb=wg&15 (batch rows gb*16..+15), gc=wg>>4 (units gc*16..+15).
// Layer1 one step behind layer0 -> 1 flag barrier / round. h exchange staged via LDS.
__global__ __launch_bounds__(256, 1)
void k_encoder(const float* __restrict__ input,
               const unsigned short* __restrict__ w0hi, const unsigned short* __restrict__ w0lo,
               const unsigned short* __restrict__ w1hi, const unsigned short* __restrict__ w1lo,
               const float* __restrict__ b0, const float* __restrict__ b1,
               unsigned short* h0h, unsigned short* h0l,
               unsigned short* h1h, unsigned short* h1l,
               float* __restrict__ cfin, unsigned* flags)
{
  const int wg = blockIdx.x;
  const int gb = wg & 15, gc = wg >> 4;
  const int tid = threadIdx.x;
  const int wid = tid >> 6, lane = tid & 63;
  const int lcol = lane & 15, lrow = lane >> 4;
  const int r0 = gb * 16, u0 = gc * 16;
  const int wrow = wid * 256 + u0 + lcol;

  __shared__ char s_h0[2][8192];   // [hi/lo] h0(k-1): 16 rows x 512B (swizzled)
  __shared__ char s_h1[2][8192];   // [hi/lo] h1(k-2)
  __shared__ float gA[4][16][17];
  __shared__ float gB[4][16][17];
  __shared__ float cb[2][16][16];

  cb[0][tid >> 4][tid & 15] = 0.f;
  cb[1][tid >> 4][tid & 15] = 0.f;

  // weights resident in VGPRs (bf16 hi+lo)
  bf16x8 w0h_[9], w0l_[9], w1h_[16], w1l_[16];
  {
    const unsigned short* p = w0hi + (size_t)wrow * 288 + lrow * 8;
    const unsigned short* q = w0lo + (size_t)wrow * 288 + lrow * 8;
    #pragma unroll
    for (int kk = 0; kk < 9; ++kk) {
      w0h_[kk] = *(const bf16x8*)(p + kk * 32);
      w0l_[kk] = *(const bf16x8*)(q + kk * 32);
    }
    const unsigned short* p1 = w1hi + (size_t)wrow * 512 + lrow * 8;
    const unsigned short* q1 = w1lo + (size_t)wrow * 512 + lrow * 8;
    #pragma unroll
    for (int kk = 0; kk < 16; ++kk) {
      w1h_[kk] = *(const bf16x8*)(p1 + kk * 32);
      w1l_[kk] = *(const bf16x8*)(q1 + kk * 32);
    }
  }
  const float bias0 = b0[wrow];
  const float bias1 = b1[wrow];
  unsigned* gflags = flags + gb * 64;
  __syncthreads();

  for (int k = 0; k <= 512; ++k) {
    const int rp = (k - 1) & 1;   // h0 read parity; h1 write parity
    const int wp = k & 1;         // h0 write parity; h1 read parity

    // ---- stage h0(rp) pair + h1(wp) pair -> LDS (16 x 8B coherent loads/thread)
    {
      #pragma unroll
      for (int i = 0; i < 16; ++i) {
        const unsigned short* src = (i < 4) ? (h0h + rp * 65536)
                                  : (i < 8) ? (h0l + rp * 65536)
                                  : (i < 12) ? (h1h + wp * 65536)
                                             : (h1l + wp * 65536);
        char* dst = (i < 4) ? s_h0[0] : (i < 8) ? s_h0[1] : (i < 12) ? s_h1[0] : s_h1[1];
        int row = (i & 3) * 4 + (tid >> 6);
        int off = tid & 63;
        unsigned long long v = ld_coh8((const unsigned long long*)(src + (size_t)(r0 + row) * 256) + off);
        *(unsigned long long*)(dst + (((row << 9) | (off << 3)) ^ ((row & 7) << 4))) = v;
      }
    }
    __syncthreads();

    // h0(k-1) fragments feed BOTH L0 (recurrent) and L1 (sequence input): hold in regs
    bf16x8 f0h[8], f0l[8];
    #pragma unroll
    for (int kk = 0; kk < 8; ++kk) {
      f0h[kk] = LDSF(s_h0[0], lcol, kk);
      f0l[kk] = LDSF(s_h0[1], lcol, kk);
    }

    if (k < 512) {  // ---- layer0 step k
      union { bf16x8 v; unsigned short s[8]; } xh, xl;
      {
        const float* px = input + (size_t)(r0 + lcol) * 16384 + (size_t)k * 32 + lrow * 8;
        f32x4 a = *(const f32x4*)px;
        f32x4 b = *(const f32x4*)(px + 4);
        #pragma unroll
        for (int j = 0; j < 4; ++j) {
          unsigned short t1 = f2bf(a[j]); xh.s[j] = t1;     xl.s[j]     = f2bf(a[j] - bf2f(t1));
          unsigned short t2 = f2bf(b[j]); xh.s[4 + j] = t2; xl.s[4 + j] = f2bf(b[j] - bf2f(t2));
        }
      }
      f32x4 ahh = {0.f,0.f,0.f,0.f}, ahl = {0.f,0.f,0.f,0.f}, alh = {0.f,0.f,0.f,0.f};
      ahh = MFMA16(xh.v, w0h_[0], ahh);
      ahl = MFMA16(xh.v, w0l_[0], ahl);
      alh = MFMA16(xl.v, w0h_[0], alh);
      #pragma unroll
      for (int kk = 0; kk < 8; ++kk) {
        ahh = MFMA16(f0h[kk], w0h_[kk + 1], ahh);
        ahl = MFMA16(f0h[kk], w0l_[kk + 1], ahl);
        alh = MFMA16(f0l[kk], w0h_[kk + 1], alh);
      }
      f32x4 g = ahh + ahl + alh;
      #pragma unroll
      for (int r = 0; r < 4; ++r) gA[wid][lrow * 4 + r][lcol] = g[r] + bias0;
    }
    if (k >= 1) {   // ---- layer1 step k-1 : A = [h0(k-1) | h1(k-2)]
      f32x4 ahh = {0.f,0.f,0.f,0.f}, ahl = {0.f,0.f,0.f,0.f}, alh = {0.f,0.f,0.f,0.f};
      #pragma unroll
      for (int kk = 0; kk < 8; ++kk) {
        ahh = MFMA16(f0h[kk], w1h_[kk], ahh);
        ahl = MFMA16(f0h[kk], w1l_[kk], ahl);
        alh = MFMA16(f0l[kk], w1h_[kk], alh);
      }
      #pragma unroll
      for (int kk = 0; kk < 8; ++kk) {
        bf16x8 fh_ = LDSF(s_h1[0], lcol, kk);
        bf16x8 fl_ = LDSF(s_h1[1], lcol, kk);
        ahh = MFMA16(fh_, w1h_[kk + 8], ahh);
        ahl = MFMA16(fh_, w1l_[kk + 8], ahl);
        alh = MFMA16(fl_, w1h_[kk + 8], alh);
      }
      f32x4 g = ahh + ahl + alh;
      #pragma unroll
      for (int r = 0; r < 4; ++r) gB[wid][lrow * 4 + r][lcol] = g[r] + bias1;
    }
    __syncthreads();

    const int urow = tid >> 4, uu = tid & 15;
    if (k < 512) {
      float gi = gA[0][urow][uu], gf = gA[1][urow][uu];
      float gg = gA[2][urow][uu], go = gA[3][urow][uu];
      float c = sigf(gf) * cb[0][urow][uu] + sigf(gi) * tanhsafe(gg);
      cb[0][urow][uu] = c;
      float h = sigf(go) * tanhsafe(c);
      size_t off = (size_t)wp * 65536 + (size_t)(r0 + urow) * 256 + (u0 + uu);
      st_hpair(h, h0h + off, h0l + off);
    }
    if (k >= 1) {
      float gi = gB[0][urow][uu], gf = gB[1][urow][uu];
      float gg = gB[2][urow][uu], go = gB[3][urow][uu];
      float c = sigf(gf) * cb[1][urow][uu] + sigf(gi) * tanhsafe(gg);
      cb[1][urow][uu] = c;
      float h = sigf(go) * tanhsafe(c);
      size_t off = (size_t)rp * 65536 + (size_t)(r0 + urow) * 256 + (u0 + uu);
      st_hpair(h, h1h + off, h1l + off);
    }
    flag_barrier(gflags, gc, (unsigned)(k + 1));
  }

  const int urow = tid >> 4, uu = tid & 15;
  cfin[(size_t)(r0 + urow) * 256 + (u0 + uu)] = cb[0][urow][uu];
  cfin[65536 + (size_t)(r0 + urow) * 256 + (u0 + uu)] = cb[1][urow][uu];
}

// ---------------- decoder ----------------
// L0 gates = h1 @ Weff^T + h0 @ Whh0^T + beff   (x-feedback folded: Weff = Wih0@fcW)
// L1 gates = h0' @ Wih1^T + h1 @ Whh1^T + b1
// pred(t-1) = h1(t-1) @ fcW^T + fcb computed redundantly per group via MFMA in phase A of t
// (waves 0/1, fcW hi/lo from LDS); only gc==0 stores. Time-reversed slots.
// D-fragment layout: row (=batch here) = lrow*4+reg, col (=fc column) = lcol.
__global__ __launch_bounds__(256, 1)
void k_decoder(const unsigned short* __restrict__ w0hi, const unsigned short* __restrict__ w0lo,
               const unsigned short* __restrict__ w1hi, const unsigned short* __restrict__ w1lo,
               const float* __restrict__ beff, const float* __restrict__ db0,
               const float* __restrict__ b1, const float* __restrict__ fcb,
               const unsigned short* __restrict__ fcwh_g, const unsigned short* __restrict__ fcwl_g,
               unsigned short* h0h, unsigned short* h0l,
               unsigned short* h1h, unsigned short* h1l,
               const float* __restrict__ cfin, float* __restrict__ out, unsigned* flags)
{
  const int wg = blockIdx.x;
  const int gb = wg & 15, gc = wg >> 4;
  const int tid = threadIdx.x;
  const int wid = tid >> 6, lane = tid & 63;
  const int lcol = lane & 15, lrow = lane >> 4;
  const int r0 = gb * 16, u0 = gc * 16;
  const int wrow = wid * 256 + u0 + lcol;

  __shared__ char s_h1[2][8192];        // [hi/lo] h1(t-1)
  __shared__ char s_h0[2][2][8192];     // [parity][hi/lo]
  __shared__ char s_fcw[2][16384];      // [hi/lo] fcW [32 rows][512B] swizzled
  __shared__ float gA[4][16][17];
  __shared__ float cb[2][16][16];

  {
    const int urow = tid >> 4, uu = tid & 15;
    cb[0][urow][uu] = cfin[(size_t)(r0 + urow) * 256 + (u0 + uu)];
    cb[1][urow][uu] = cfin[65536 + (size_t)(r0 + urow) * 256 + (u0 + uu)];
  }
  // stage fcW (constant) into LDS, swizzled; plain loads (prep kernel ordered on stream)
  {
    #pragma unroll
    for (int i = 0; i < 16; ++i) {
      const unsigned short* src = (i < 8) ? fcwh_g : fcwl_g;
      char* dst = (i < 8) ? s_fcw[0] : s_fcw[1];
      int row = (i & 7) * 4 + (tid >> 6);
      int off = tid & 63;
      unsigned long long v = *((const unsigned long long*)(src + (size_t)row * 256) + off);
      *(unsigned long long*)(dst + (((row << 9) | (off << 3)) ^ ((row & 7) << 4))) = v;
    }
  }
  // prologue stage: h1(par1), h0(par1) from encoder finals
  {
    #pragma unroll
    for (int i = 0; i < 16; ++i) {
      const unsigned short* src = (i < 4) ? (h1h + 65536)
                                : (i < 8) ? (h1l + 65536)
                                : (i < 12) ? (h0h + 65536)
                                           : (h0l + 65536);
      char* dst = (i < 4) ? s_h1[0] : (i < 8) ? s_h1[1] : (i < 12) ? s_h0[1][0] : s_h0[1][1];
      int row = (i & 3) * 4 + (tid >> 6);
      int off = tid & 63;
      unsigned long long v = ld_coh8((const unsigned long long*)(src + (size_t)(r0 + row) * 256) + off);
      *(unsigned long long*)(dst + (((row << 9) | (off << 3)) ^ ((row & 7) << 4))) = v;
    }
  }

  // weights resident in VGPRs
  bf16x8 w0h_[16], w0l_[16], w1h_[16], w1l_[16];
  {
    const unsigned short* p = w0hi + (size_t)wrow * 512 + lrow * 8;
    const unsigned short* q = w0lo + (size_t)wrow * 512 + lrow * 8;
    #pragma unroll
    for (int kk = 0; kk < 16; ++kk) {
      w0h_[kk] = *(const bf16x8*)(p + kk * 32);
      w0l_[kk] = *(const bf16x8*)(q + kk * 32);
    }
    const unsigned short* p1 = w1hi + (size_t)wrow * 512 + lrow * 8;
    const unsigned short* q1 = w1lo + (size_t)wrow * 512 + lrow * 8;
    #pragma unroll
    for (int kk = 0; kk < 16; ++kk) {
      w1h_[kk] = *(const bf16x8*)(p1 + kk * 32);
      w1l_[kk] = *(const bf16x8*)(q1 + kk * 32);
    }
  }
  const float bias0 = beff[wrow], bias0t0 = db0[wrow], bias1 = b1[wrow];
  // fc bias for this lane's output column (waves 0/1 compute pred cols wid*16+lcol)
  const float fcbv = (wid < 2) ? fcb[wid * 16 + lcol] : 0.f;
  unsigned* gflags = flags + gb * 64;
  __syncthreads();

  bf16x8 h1h_r[8], h1l_r[8];

  for (int t = 0; t < 512; ++t) {
    const int wp = t & 1, rp = 1 - wp;

    // ================= phase A : layer0 (+ pred(t-1)) =================
    if (t > 0) {  // stage h1(rp); (h0(rp) already staged by phase B of t-1)
      #pragma unroll
      for (int i = 0; i < 8; ++i) {
        const unsigned short* src = (i < 4) ? (h1h + rp * 65536) : (h1l + rp * 65536);
        char* dst = (i < 4) ? s_h1[0] : s_h1[1];
        int row = (i & 3) * 4 + (tid >> 6);
        int off = tid & 63;
        unsigned long long v = ld_coh8((const unsigned long long*)(src + (size_t)(r0 + row) * 256) + off);
        *(unsigned long long*)(dst + (((row << 9) | (off << 3)) ^ ((row & 7) << 4))) = v;
      }
    }
    __syncthreads();

    #pragma unroll
    for (int kk = 0; kk < 8; ++kk) {   // h1 frags: used in A (Weff, pred) and B (Whh1)
      h1h_r[kk] = LDSF(s_h1[0], lcol, kk);
      h1l_r[kk] = LDSF(s_h1[1], lcol, kk);
    }

    {
      f32x4 ahh = {0.f,0.f,0.f,0.f}, ahl = {0.f,0.f,0.f,0.f}, alh = {0.f,0.f,0.f,0.f};
      if (t > 0) {
        #pragma unroll
        for (int kk = 0; kk < 8; ++kk) {
          ahh = MFMA16(h1h_r[kk], w0h_[kk], ahh);
          ahl = MFMA16(h1h_r[kk], w0l_[kk], ahl);
          alh = MFMA16(h1l_r[kk], w0h_[kk], alh);
        }
        if (wid < 2) {  // pred(t-1) = h1(t-1) @ fcW^T + fcb : waves 0/1, cols wid*16..+15
          f32x4 p0 = {0.f,0.f,0.f,0.f}, p1 = {0.f,0.f,0.f,0.f}, p2 = {0.f,0.f,0.f,0.f};
          #pragma unroll
          for (int kk = 0; kk < 8; ++kk) {
            bf16x8 fh_ = LDSF(s_fcw[0], wid * 16 + lcol, kk);
            bf16x8 fl_ = LDSF(s_fcw[1], wid * 16 + lcol, kk);
            p0 = MFMA16(h1h_r[kk], fh_, p0);
            p1 = MFMA16(h1h_r[kk], fl_, p1);
            p2 = MFMA16(h1l_r[kk], fh_, p2);
          }
          if (gc == 0) {
            // D[row=batch=lrow*4+j][col=fc-col=lcol]
            #pragma unroll
            for (int j = 0; j < 4; ++j)
              out[(size_t)(r0 + lrow * 4 + j) * 16384 + (size_t)(512 - t) * 32 + wid * 16 + lcol] =
                  p0[j] + p1[j] + p2[j] + fcbv;
          }
        }
      }
      #pragma unroll
      for (int kk = 0; kk < 8; ++kk) {
        bf16x8 fh_ = LDSF(s_h0[rp][0], lcol, kk);
        bf16x8 fl_ = LDSF(s_h0[rp][1], lcol, kk);
        ahh = MFMA16(fh_, w0h_[kk + 8], ahh);
        ahl = MFMA16(fh_, w0l_[kk + 8], ahl);
        alh = MFMA16(fl_, w0h_[kk + 8], alh);
      }
      f32x4 g = ahh + ahl + alh;
      float bb = (t == 0) ? bias0t0 : bias0;
      #pragma unroll
      for (int r = 0; r < 4; ++r) gA[wid][lrow * 4 + r][lcol] = g[r] + bb;
    }
    __syncthreads();
    {
      const int urow = tid >> 4, uu = tid & 15;
      float gi = gA[0][urow][uu], gf = gA[1][urow][uu];
      float gg = gA[2][urow][uu], go = gA[3][urow][uu];
      float c = sigf(gf) * cb[0][urow][uu] + sigf(gi) * tanhsafe(gg);
      cb[0][urow][uu] = c;
      float h = sigf(go) * tanhsafe(c);
      size_t off = (size_t)wp * 65536 + (size_t)(r0 + urow) * 256 + (u0 + uu);
      st_hpair(h, h0h + off, h0l + off);
    }
    flag_barrier(gflags, gc, (unsigned)(2 * t + 1));

    // ================= phase B : layer1 =================
    {   // stage fresh h0'(wp)
      #pragma unroll
      for (int i = 0; i < 8; ++i) {
        const unsigned short* src = (i < 4) ? (h0h + wp * 65536) : (h0l + wp * 65536);
        char* dst = (i < 4) ? s_h0[wp][0] : s_h0[wp][1];
        int row = (i & 3) * 4 + (tid >> 6);
        int off = tid & 63;
        unsigned long long v = ld_coh8((const unsigned long long*)(src + (size_t)(r0 + row) * 256) + off);
        *(unsigned long long*)(dst + (((row << 9) | (off << 3)) ^ ((row & 7) << 4))) = v;
      }
    }
    __syncthreads();
    {
      f32x4 ahh = {0.f,0.f,0.f,0.f}, ahl = {0.f,0.f,0.f,0.f}, alh = {0.f,0.f,0.f,0.f};
      #pragma unroll
      for (int kk = 0; kk < 8; ++kk) {
        bf16x8 fh_ = LDSF(s_h0[wp][0], lcol, kk);
        bf16x8 fl_ = LDSF(s_h0[wp][1], lcol, kk);
        ahh = MFMA16(fh_, w1h_[kk], ahh);
        ahl = MFMA16(fh_, w1l_[kk], ahl);
        alh = MFMA16(fl_, w1h_[kk], alh);
      }
      #pragma unroll
      for (int kk = 0; kk < 8; ++kk) {
        ahh = MFMA16(h1h_r[kk], w1h_[kk + 8], ahh);
        ahl = MFMA16(h1h_r[kk], w1l_[kk + 8], ahl);
        alh = MFMA16(h1l_r[kk], w1h_[kk + 8], alh);
      }
      f32x4 g = ahh + ahl + alh;
      #pragma unroll
      for (int r = 0; r < 4; ++r) gA[wid][lrow * 4 + r][lcol] = g[r] + bias1;
    }
    __syncthreads();
    {
      const int urow = tid >> 4, uu = tid & 15;
      float gi = gA[0][urow][uu], gf = gA[1][urow][uu];
      float gg = gA[2][urow][uu], go = gA[3][urow][uu];
      float c = sigf(gf) * cb[1][urow][uu] + sigf(gi) * tanhsafe(gg);
      cb[1][urow][uu] = c;
      float h = sigf(go) * tanhsafe(c);
      size_t off = (size_t)wp * 65536 + (size_t)(r0 + urow) * 256 + (u0 + uu);
      st_hpair(h, h1h + off, h1l + off);
    }
    flag_barrier(gflags, gc, (unsigned)(2 * t + 2));
  }

  // ---- tail: pred(511) from h1(par1) -> slot 0
  {
    #pragma unroll
    for (int i = 0; i < 8; ++i) {
      const unsigned short* src = (i < 4) ? (h1h + 65536) : (h1l + 65536);
      char* dst = (i < 4) ? s_h1[0] : s_h1[1];
      int row = (i & 3) * 4 + (tid >> 6);
      int off = tid & 63;
      unsigned long long v = ld_coh8((const unsigned long long*)(src + (size_t)(r0 + row) * 256) + off);
      *(unsigned long long*)(dst + (((row << 9) | (off << 3)) ^ ((row & 7) << 4))) = v;
    }
  }
  __syncthreads();
  if (wid < 2) {
    f32x4 p0 = {0.f,0.f,0.f,0.f}, p1 = {0.f,0.f,0.f,0.f}, p2 = {0.f,0.f,0.f,0.f};
    #pragma unroll
    for (int kk = 0; kk < 8; ++kk) {
      bf16x8 ah = LDSF(s_h1[0], lcol, kk);
      bf16x8 al = LDSF(s_h1[1], lcol, kk);
      bf16x8 fh_ = LDSF(s_fcw[0], wid * 16 + lcol, kk);
      bf16x8 fl_ = LDSF(s_fcw[1], wid * 16 + lcol, kk);
      p0 = MFMA16(ah, fh_, p0);
      p1 = MFMA16(ah, fl_, p1);
      p2 = MFMA16(al, fh_, p2);
    }
    if (gc == 0) {
      #pragma unroll
      for (int j = 0; j < 4; ++j)
        out[(size_t)(r0 + lrow * 4 + j) * 16384 + wid * 16 + lcol] = p0[j] + p1[j] + p2[j] + fcbv;
    }
  }
}

// ---------------- launch ----------------
extern "C" void kernel_launch(void* const* d_in, const int* in_sizes, int n_in,
                              void* d_out, int out_size, void* d_ws, size_t ws_size,
                              hipStream_t stream) {
  (void)in_sizes; (void)n_in; (void)ws_size;
  const float* input = (const float*)d_in[0];
  const float* eWih0 = (const float*)d_in[1];
  const float* eWhh0 = (const float*)d_in[2];
  const float* eb0   = (const float*)d_in[3];
  const float* eWih1 = (const float*)d_in[4];
  const float* eWhh1 = (const float*)d_in[5];
  const float* eb1   = (const float*)d_in[6];
  const float* dWih0 = (const float*)d_in[7];
  const float* dWhh0 = (const float*)d_in[8];
  const float* db0   = (const float*)d_in[9];
  const float* dWih1 = (const float*)d_in[10];
  const float* dWhh1 = (const float*)d_in[11];
  const float* db1   = (const float*)d_in[12];
  const float* fcW   = (const float*)d_in[13];
  const float* fcb   = (const float*)d_in[14];

  char* ws = (char*)d_ws;
  unsigned short* h0h = (unsigned short*)(ws + OFF_H0H);
  unsigned short* h0l = (unsigned short*)(ws + OFF_H0L);
  unsigned short* h1h = (unsigned short*)(ws + OFF_H1H);
  unsigned short* h1l = (unsigned short*)(ws + OFF_H1L);
  float* cfin = (float*)(ws + OFF_CFIN);
  unsigned short* ew0h = (unsigned short*)(ws + OFF_EW0H);
  unsigned short* ew0l = (unsigned short*)(ws + OFF_EW0L);
  unsigned short* ew1h = (unsigned short*)(ws + OFF_EW1H);
  unsigned short* ew1l = (unsigned short*)(ws + OFF_EW1L);
  unsigned short* dw0h = (unsigned short*)(ws + OFF_DW0H);
  unsigned short* dw0l = (unsigned short*)(ws + OFF_DW0L);
  unsigned short* dw1h = (unsigned short*)(ws + OFF_DW1H);
  unsigned short* dw1l = (unsigned short*)(ws + OFF_DW1L);
  float* beff = (float*)(ws + OFF_BEFF);
  unsigned short* fcwh = (unsigned short*)(ws + OFF_FCWH);
  unsigned short* fcwl = (unsigned short*)(ws + OFF_FCWL);
  unsigned* eflg = (unsigned*)(ws + OFF_EFLG);
  unsigned* dflg = (unsigned*)(ws + OFF_DFLG);

  hipMemsetAsync(d_out, 0, (size_t)out_size * sizeof(float), stream);
  hipMemsetAsync(ws + OFF_H0H, 0, (size_t)4 * SZ_HBUF, stream);   // zero initial h state
  hipMemsetAsync(ws + OFF_EFLG, 0, 8192, stream);                 // barrier flags

  k_prep_cat<<<1024, 256, 0, stream>>>(1024, eWih0, 32,  eWhh0, 256, ew0h, ew0l);
  k_prep_cat<<<1024, 256, 0, stream>>>(1024, eWih1, 256, eWhh1, 256, ew1h, ew1l);
  k_prep_cat<<<1024, 256, 0, stream>>>(1024, dWih1, 256, dWhh1, 256, dw1h, dw1l);
  k_prep_cat<<<64, 256, 0, stream>>>(32, fcW, 256, fcW, 0, fcwh, fcwl);
  k_prep_dec0<<<1024, 256, 0, stream>>>(dWih0, dWhh0, fcW, dw0h, dw0l);
  k_prep_beff<<<4, 256, 0, stream>>>(dWih0, db0, fcb, beff);

  k_encoder<<<256, 256, 0, stream>>>(input, ew0h, ew0l, ew1h, ew1l, eb0, eb1,
                                     h0h, h0l, h1h, h1l, cfin, eflg);
  k_decoder<<<256, 256, 0, stream>>>(dw0h, dw0l, dw1h, dw1l, beff, db0, db1, fcb,
                                     fcwh, fcwl, h0h, h0l, h1h, h1l, cfin,
                                     (float*)d_out, dflg);
}

// Round 4
// 4124.564 us; speedup vs baseline: 3.3223x; 2.0489x over previous
//
#include <hip/hip_runtime.h>

typedef __attribute__((ext_vector_type(8))) short bf16x8;
typedef __attribute__((ext_vector_type(4))) float f32x4;

#define MFMA16(a,b,c) __builtin_amdgcn_mfma_f32_16x16x32_bf16((a),(b),(c),0,0,0)

// ---------------- sizes ----------------
// B=256 T=512 D=32 H=256 4H=1024

// ---------------- ws layout (bytes) ----------------
#define SZ_HBUF   (2*256*256*2)              // one h array: [2 parity][256 b][256 u] bf16
#define OFF_H0H   0
#define OFF_H0L   (OFF_H0H + SZ_HBUF)
#define OFF_H1H   (OFF_H0L + SZ_HBUF)
#define OFF_H1L   (OFF_H1H + SZ_HBUF)
#define OFF_CFIN  (OFF_H1L + SZ_HBUF)        // [2 layer][256][256] f32 = 524288
#define OFF_EW0H  (OFF_CFIN + 524288)        // enc L0 cat [1024][288] bf16
#define OFF_EW0L  (OFF_EW0H + 589824)
#define OFF_EW1H  (OFF_EW0L + 589824)        // enc L1 cat [1024][512] bf16
#define OFF_EW1L  (OFF_EW1H + 1048576)
#define OFF_DW0H  (OFF_EW1L + 1048576)       // dec L0 cat [Weff|Whh0] [1024][512]
#define OFF_DW0L  (OFF_DW0H + 1048576)
#define OFF_DW1H  (OFF_DW0L + 1048576)       // dec L1 cat [Wih1|Whh1]
#define OFF_DW1L  (OFF_DW1H + 1048576)
#define OFF_BEFF  (OFF_DW1L + 1048576)       // 1024 f32
#define OFF_FCWH  (OFF_BEFF + 4096)          // fc W [32][256] bf16 hi
#define OFF_FCWL  (OFF_FCWH + 16384)
#define OFF_EFLG  (OFF_FCWL + 16384)         // encoder flags: 16 groups x 64 uints
#define OFF_DFLG  (OFF_EFLG + 4096)          // decoder flags

// ---------------- helpers ----------------
static __device__ __forceinline__ unsigned short f2bf(float f) {
  unsigned u = __float_as_uint(f);
  u = u + 0x7fffu + ((u >> 16) & 1u);
  return (unsigned short)(u >> 16);
}
static __device__ __forceinline__ float bf2f(unsigned short s) {
  return __uint_as_float(((unsigned)s) << 16);
}
static __device__ __forceinline__ float sigf(float x) {
  return 1.f / (1.f + __expf(-x));
}
static __device__ __forceinline__ float tanhsafe(float x) {
  float a = fabsf(x);
  float e = __expf(-2.f * a);
  float t = (1.f - e) / (1.f + e);
  return x < 0.f ? -t : t;
}
// split h into bf16 hi+lo and store coherently (agent scope)
static __device__ __forceinline__ void st_hpair(float h, unsigned short* ph, unsigned short* pl) {
  unsigned short hi = f2bf(h);
  unsigned short lo = f2bf(h - bf2f(hi));
  __hip_atomic_store(ph, hi, __ATOMIC_RELAXED, __HIP_MEMORY_SCOPE_AGENT);
  __hip_atomic_store(pl, lo, __ATOMIC_RELAXED, __HIP_MEMORY_SCOPE_AGENT);
}
// pipelined coherent 16B load: issue-only (data valid after wait_vm0())
static __device__ __forceinline__ f32x4 ld16(const void* p) {
  f32x4 d;
  asm volatile("global_load_dwordx4 %0, %1, off sc0 sc1" : "=&v"(d) : "v"(p) : "memory");
  return d;
}
static __device__ __forceinline__ void wait_vm0() {
  asm volatile("s_waitcnt vmcnt(0)" ::: "memory");
  __builtin_amdgcn_sched_barrier(0);
}
// flag barrier: each WG publishes monotonically-increasing round; wave0 polls 16 flags in one load
static __device__ __forceinline__ void flag_barrier(unsigned* flags, int gc, unsigned round) {
  __syncthreads();                 // all waves drain their agent-visible stores
  if (threadIdx.x == 0)
    __hip_atomic_store(flags + gc, round, __ATOMIC_RELAXED, __HIP_MEMORY_SCOPE_AGENT);
  if (threadIdx.x < 64) {
    int l = threadIdx.x;
    for (;;) {
      unsigned v = (l < 16) ? __hip_atomic_load(flags + l, __ATOMIC_RELAXED, __HIP_MEMORY_SCOPE_AGENT)
                            : round;
      if (__all((int)(v >= round))) break;
    }
  }
  __syncthreads();
}

// swizzled LDS fragment read: 16B at (row*512 | lrow*16 | kk*64) ^ ((row&7)<<4)
#define LDSF(base, row, kk) \
  (*(const bf16x8*)((base) + ((((row) << 9) | (lrow << 4) | ((kk) << 6)) ^ (((row) & 7) << 4))))

// ---------------- prep kernels ----------------
__global__ void k_prep_cat(int nrows, const float* __restrict__ s0, int K0,
                           const float* __restrict__ s1, int K1,
                           unsigned short* __restrict__ whi, unsigned short* __restrict__ wlo) {
  int K = K0 + K1;
  int tot = nrows * K;
  for (int idx = blockIdx.x * blockDim.x + threadIdx.x; idx < tot; idx += gridDim.x * blockDim.x) {
    int n = idx / K, k = idx - n * K;
    float v = (k < K0) ? s0[n * K0 + k] : s1[n * K1 + (k - K0)];
    unsigned short hi = f2bf(v);
    unsigned short lo = f2bf(v - bf2f(hi));
    whi[idx] = hi; wlo[idx] = lo;
  }
}
// dec L0 cat: cols 0..255 = Weff = Wih0 @ fcW, cols 256..511 = Whh0
__global__ void k_prep_dec0(const float* __restrict__ Wih0, const float* __restrict__ Whh0,
                            const float* __restrict__ fcW,
                            unsigned short* __restrict__ whi, unsigned short* __restrict__ wlo) {
  int tot = 1024 * 512;
  for (int idx = blockIdx.x * blockDim.x + threadIdx.x; idx < tot; idx += gridDim.x * blockDim.x) {
    int n = idx >> 9, k = idx & 511;
    float v;
    if (k < 256) {
      v = 0.f;
      #pragma unroll
      for (int d = 0; d < 32; ++d) v += Wih0[n * 32 + d] * fcW[d * 256 + k];
    } else {
      v = Whh0[n * 256 + (k - 256)];
    }
    unsigned short hi = f2bf(v);
    unsigned short lo = f2bf(v - bf2f(hi));
    whi[idx] = hi; wlo[idx] = lo;
  }
}
__global__ void k_prep_beff(const float* __restrict__ Wih0, const float* __restrict__ b0,
                            const float* __restrict__ fcb, float* __restrict__ beff) {
  int n = blockIdx.x * blockDim.x + threadIdx.x;
  if (n < 1024) {
    float v = b0[n];
    #pragma unroll
    for (int d = 0; d < 32; ++d) v += Wih0[n * 32 + d] * fcb[d];
    beff[n] = v;
  }
}

// ---------------- encoder ----------------
// 256 WGs x 256 thr; gb=wg&15 (batch rows gb*16..+15), gc=wg>>4 (units gc*16..+15).
// Layer1 one step behind layer0 -> 1 flag barrier / round.
// Staging: batched asm dwordx4 coherent loads -> single vmcnt wait -> LDS.
__global__ __launch_bounds__(256, 1)
void k_encoder(const float* __restrict__ input,
               const unsigned short* __restrict__ w0hi, const unsigned short* __restrict__ w0lo,
               const unsigned short* __restrict__ w1hi, const unsigned short* __restrict__ w1lo,
               const float* __restrict__ b0, const float* __restrict__ b1,
               unsigned short* h0h, unsigned short* h0l,
               unsigned short* h1h, unsigned short* h1l,
               float* __restrict__ cfin, unsigned* flags)
{
  const int wg = blockIdx.x;
  const int gb = wg & 15, gc = wg >> 4;
  const int tid = threadIdx.x;
  const int wid = tid >> 6, lane = tid & 63;
  const int lcol = lane & 15, lrow = lane >> 4;
  const int r0 = gb * 16, u0 = gc * 16;
  const int wrow = wid * 256 + u0 + lcol;

  __shared__ char s_h0[2][8192];   // [hi/lo] h0(k-1): 16 rows x 512B (swizzled)
  __shared__ char s_h1[2][8192];   // [hi/lo] h1(k-2)
  __shared__ float gA[4][16][17];
  __shared__ float gB[4][16][17];
  __shared__ float cb[2][16][16];

  cb[0][tid >> 4][tid & 15] = 0.f;
  cb[1][tid >> 4][tid & 15] = 0.f;

  // staging geometry: 2 passes of 8 rows; 16B per thread per pass per array
  const int srow = (tid >> 5) & 7;                 // 0..7
  const int scol8 = (tid & 31) << 3;               // short offset in row
  const int dA = ((srow << 9) | ((tid & 31) << 4)) ^ (srow << 4);
  const int dB = dA + 4096;                        // row+8, same xor (row&7 unchanged)

  // weights resident in VGPRs (bf16 hi+lo)
  bf16x8 w0h_[9], w0l_[9], w1h_[16], w1l_[16];
  {
    const unsigned short* p = w0hi + (size_t)wrow * 288 + lrow * 8;
    const unsigned short* q = w0lo + (size_t)wrow * 288 + lrow * 8;
    #pragma unroll
    for (int kk = 0; kk < 9; ++kk) {
      w0h_[kk] = *(const bf16x8*)(p + kk * 32);
      w0l_[kk] = *(const bf16x8*)(q + kk * 32);
    }
    const unsigned short* p1 = w1hi + (size_t)wrow * 512 + lrow * 8;
    const unsigned short* q1 = w1lo + (size_t)wrow * 512 + lrow * 8;
    #pragma unroll
    for (int kk = 0; kk < 16; ++kk) {
      w1h_[kk] = *(const bf16x8*)(p1 + kk * 32);
      w1l_[kk] = *(const bf16x8*)(q1 + kk * 32);
    }
  }
  const float bias0 = b0[wrow];
  const float bias1 = b1[wrow];
  unsigned* gflags = flags + gb * 64;
  __syncthreads();

  for (int k = 0; k <= 512; ++k) {
    const int rp = (k - 1) & 1;   // h0 read parity; h1 write parity
    const int wp = k & 1;         // h0 write parity; h1 read parity

    f32x4 ahh = {0.f,0.f,0.f,0.f}, ahl = {0.f,0.f,0.f,0.f}, alh = {0.f,0.f,0.f,0.f};
    union { bf16x8 v; unsigned short s[8]; } xh, xl;
    if (k < 512) {   // x load + convert first (plain loads; their waits precede stage issues)
      const float* px = input + (size_t)(r0 + lcol) * 16384 + (size_t)k * 32 + lrow * 8;
      f32x4 a = *(const f32x4*)px;
      f32x4 b = *(const f32x4*)(px + 4);
      #pragma unroll
      for (int j = 0; j < 4; ++j) {
        unsigned short t1 = f2bf(a[j]); xh.s[j] = t1;     xl.s[j]     = f2bf(a[j] - bf2f(t1));
        unsigned short t2 = f2bf(b[j]); xh.s[4 + j] = t2; xl.s[4 + j] = f2bf(b[j] - bf2f(t2));
      }
    }

    // issue all 8 staging loads (pipelined)
    const unsigned short* p0h = h0h + (size_t)rp * 65536 + (size_t)(r0 + srow) * 256 + scol8;
    const unsigned short* p0l = h0l + (size_t)rp * 65536 + (size_t)(r0 + srow) * 256 + scol8;
    const unsigned short* p1h = h1h + (size_t)wp * 65536 + (size_t)(r0 + srow) * 256 + scol8;
    const unsigned short* p1l = h1l + (size_t)wp * 65536 + (size_t)(r0 + srow) * 256 + scol8;
    f32x4 v0 = ld16(p0h), v1 = ld16(p0h + 2048);
    f32x4 v2 = ld16(p0l), v3 = ld16(p0l + 2048);
    f32x4 v4 = ld16(p1h), v5 = ld16(p1h + 2048);
    f32x4 v6 = ld16(p1l), v7 = ld16(p1l + 2048);

    if (k < 512) {   // overlap: x MFMAs under the load shadow
      ahh = MFMA16(xh.v, w0h_[0], ahh);
      ahl = MFMA16(xh.v, w0l_[0], ahl);
      alh = MFMA16(xl.v, w0h_[0], alh);
    }

    wait_vm0();
    *(f32x4*)(s_h0[0] + dA) = v0; *(f32x4*)(s_h0[0] + dB) = v1;
    *(f32x4*)(s_h0[1] + dA) = v2; *(f32x4*)(s_h0[1] + dB) = v3;
    *(f32x4*)(s_h1[0] + dA) = v4; *(f32x4*)(s_h1[0] + dB) = v5;
    *(f32x4*)(s_h1[1] + dA) = v6; *(f32x4*)(s_h1[1] + dB) = v7;
    __syncthreads();

    // h0(k-1) fragments feed BOTH L0 (recurrent) and L1 (sequence input)
    bf16x8 f0h[8], f0l[8];
    #pragma unroll
    for (int kk = 0; kk < 8; ++kk) {
      f0h[kk] = LDSF(s_h0[0], lcol, kk);
      f0l[kk] = LDSF(s_h0[1], lcol, kk);
    }

    if (k < 512) {  // ---- layer0 step k (recurrent half)
      #pragma unroll
      for (int kk = 0; kk < 8; ++kk) {
        ahh = MFMA16(f0h[kk], w0h_[kk + 1], ahh);
        ahl = MFMA16(f0h[kk], w0l_[kk + 1], ahl);
        alh = MFMA16(f0l[kk], w0h_[kk + 1], alh);
      }
      f32x4 g = ahh + ahl + alh;
      #pragma unroll
      for (int r = 0; r < 4; ++r) gA[wid][lrow * 4 + r][lcol] = g[r] + bias0;
    }
    if (k >= 1) {   // ---- layer1 step k-1 : A = [h0(k-1) | h1(k-2)]
      f32x4 bhh = {0.f,0.f,0.f,0.f}, bhl = {0.f,0.f,0.f,0.f}, blh = {0.f,0.f,0.f,0.f};
      #pragma unroll
      for (int kk = 0; kk < 8; ++kk) {
        bhh = MFMA16(f0h[kk], w1h_[kk], bhh);
        bhl = MFMA16(f0h[kk], w1l_[kk], bhl);
        blh = MFMA16(f0l[kk], w1h_[kk], blh);
      }
      #pragma unroll
      for (int kk = 0; kk < 8; ++kk) {
        bf16x8 fh_ = LDSF(s_h1[0], lcol, kk);
        bf16x8 fl_ = LDSF(s_h1[1], lcol, kk);
        bhh = MFMA16(fh_, w1h_[kk + 8], bhh);
        bhl = MFMA16(fh_, w1l_[kk + 8], bhl);
        blh = MFMA16(fl_, w1h_[kk + 8], blh);
      }
      f32x4 g = bhh + bhl + blh;
      #pragma unroll
      for (int r = 0; r < 4; ++r) gB[wid][lrow * 4 + r][lcol] = g[r] + bias1;
    }
    __syncthreads();

    const int urow = tid >> 4, uu = tid & 15;
    if (k < 512) {
      float gi = gA[0][urow][uu], gf = gA[1][urow][uu];
      float gg = gA[2][urow][uu], go = gA[3][urow][uu];
      float c = sigf(gf) * cb[0][urow][uu] + sigf(gi) * tanhsafe(gg);
      cb[0][urow][uu] = c;
      float h = sigf(go) * tanhsafe(c);
      size_t off = (size_t)wp * 65536 + (size_t)(r0 + urow) * 256 + (u0 + uu);
      st_hpair(h, h0h + off, h0l + off);
    }
    if (k >= 1) {
      float gi = gB[0][urow][uu], gf = gB[1][urow][uu];
      float gg = gB[2][urow][uu], go = gB[3][urow][uu];
      float c = sigf(gf) * cb[1][urow][uu] + sigf(gi) * tanhsafe(gg);
      cb[1][urow][uu] = c;
      float h = sigf(go) * tanhsafe(c);
      size_t off = (size_t)rp * 65536 + (size_t)(r0 + urow) * 256 + (u0 + uu);
      st_hpair(h, h1h + off, h1l + off);
    }
    flag_barrier(gflags, gc, (unsigned)(k + 1));
  }

  const int urow = tid >> 4, uu = tid & 15;
  cfin[(size_t)(r0 + urow) * 256 + (u0 + uu)] = cb[0][urow][uu];
  cfin[65536 + (size_t)(r0 + urow) * 256 + (u0 + uu)] = cb[1][urow][uu];
}

// ---------------- decoder ----------------
// L0 gates = h1 @ Weff^T + h0 @ Whh0^T + beff   (x-feedback folded: Weff = Wih0@fcW)
// L1 gates = h0' @ Wih1^T + h1 @ Whh1^T + b1
// pred(t-1) = h1(t-1) @ fcW^T + fcb computed in phase B's overlap window (h1 regs),
// waves 0/1, only gc==0 stores. Time-reversed slots.
// Per phase: issue loads -> old-operand MFMA half under shadow -> wait -> LDS -> new half.
__global__ __launch_bounds__(256, 1)
void k_decoder(const unsigned short* __restrict__ w0hi, const unsigned short* __restrict__ w0lo,
               const unsigned short* __restrict__ w1hi, const unsigned short* __restrict__ w1lo,
               const float* __restrict__ beff, const float* __restrict__ db0,
               const float* __restrict__ b1, const float* __restrict__ fcb,
               const unsigned short* __restrict__ fcwh_g, const unsigned short* __restrict__ fcwl_g,
               unsigned short* h0h, unsigned short* h0l,
               unsigned short* h1h, unsigned short* h1l,
               const float* __restrict__ cfin, float* __restrict__ out, unsigned* flags)
{
  const int wg = blockIdx.x;
  const int gb = wg & 15, gc = wg >> 4;
  const int tid = threadIdx.x;
  const int wid = tid >> 6, lane = tid & 63;
  const int lcol = lane & 15, lrow = lane >> 4;
  const int r0 = gb * 16, u0 = gc * 16;
  const int wrow = wid * 256 + u0 + lcol;

  __shared__ char s_h1[2][8192];        // [hi/lo] h1(t-1)
  __shared__ char s_h0[2][2][8192];     // [parity][hi/lo]
  __shared__ char s_fcw[2][16384];      // [hi/lo] fcW [32 rows][512B] swizzled
  __shared__ float gA[4][16][17];
  __shared__ float cb[2][16][16];

  const int srow = (tid >> 5) & 7;
  const int scol8 = (tid & 31) << 3;
  const int dA = ((srow << 9) | ((tid & 31) << 4)) ^ (srow << 4);
  const int dB = dA + 4096;

  {
    const int urow = tid >> 4, uu = tid & 15;
    cb[0][urow][uu] = cfin[(size_t)(r0 + urow) * 256 + (u0 + uu)];
    cb[1][urow][uu] = cfin[65536 + (size_t)(r0 + urow) * 256 + (u0 + uu)];
  }
  // prologue staging: h1(par1), h0(par1), fcW — all batched
  {
    const unsigned short* q1h = h1h + 65536 + (size_t)(r0 + srow) * 256 + scol8;
    const unsigned short* q1l = h1l + 65536 + (size_t)(r0 + srow) * 256 + scol8;
    const unsigned short* q0h = h0h + 65536 + (size_t)(r0 + srow) * 256 + scol8;
    const unsigned short* q0l = h0l + 65536 + (size_t)(r0 + srow) * 256 + scol8;
    f32x4 v0 = ld16(q1h), v1 = ld16(q1h + 2048);
    f32x4 v2 = ld16(q1l), v3 = ld16(q1l + 2048);
    f32x4 v4 = ld16(q0h), v5 = ld16(q0h + 2048);
    f32x4 v6 = ld16(q0l), v7 = ld16(q0l + 2048);
    f32x4 fh0 = ld16(fcwh_g + (size_t)srow * 256 + scol8);
    f32x4 fh1 = ld16(fcwh_g + (size_t)(srow + 8) * 256 + scol8);
    f32x4 fh2 = ld16(fcwh_g + (size_t)(srow + 16) * 256 + scol8);
    f32x4 fh3 = ld16(fcwh_g + (size_t)(srow + 24) * 256 + scol8);
    f32x4 fl0 = ld16(fcwl_g + (size_t)srow * 256 + scol8);
    f32x4 fl1 = ld16(fcwl_g + (size_t)(srow + 8) * 256 + scol8);
    f32x4 fl2 = ld16(fcwl_g + (size_t)(srow + 16) * 256 + scol8);
    f32x4 fl3 = ld16(fcwl_g + (size_t)(srow + 24) * 256 + scol8);
    wait_vm0();
    *(f32x4*)(s_h1[0] + dA) = v0;    *(f32x4*)(s_h1[0] + dB) = v1;
    *(f32x4*)(s_h1[1] + dA) = v2;    *(f32x4*)(s_h1[1] + dB) = v3;
    *(f32x4*)(s_h0[1][0] + dA) = v4; *(f32x4*)(s_h0[1][0] + dB) = v5;
    *(f32x4*)(s_h0[1][1] + dA) = v6; *(f32x4*)(s_h0[1][1] + dB) = v7;
    *(f32x4*)(s_fcw[0] + dA) = fh0;          *(f32x4*)(s_fcw[0] + dA + 4096) = fh1;
    *(f32x4*)(s_fcw[0] + dA + 8192) = fh2;   *(f32x4*)(s_fcw[0] + dA + 12288) = fh3;
    *(f32x4*)(s_fcw[1] + dA) = fl0;          *(f32x4*)(s_fcw[1] + dA + 4096) = fl1;
    *(f32x4*)(s_fcw[1] + dA + 8192) = fl2;   *(f32x4*)(s_fcw[1] + dA + 12288) = fl3;
  }

  // weights resident in VGPRs
  bf16x8 w0h_[16], w0l_[16], w1h_[16], w1l_[16];
  {
    const unsigned short* p = w0hi + (size_t)wrow * 512 + lrow * 8;
    const unsigned short* q = w0lo + (size_t)wrow * 512 + lrow * 8;
    #pragma unroll
    for (int kk = 0; kk < 16; ++kk) {
      w0h_[kk] = *(const bf16x8*)(p + kk * 32);
      w0l_[kk] = *(const bf16x8*)(q + kk * 32);
    }
    const unsigned short* p1 = w1hi + (size_t)wrow * 512 + lrow * 8;
    const unsigned short* q1 = w1lo + (size_t)wrow * 512 + lrow * 8;
    #pragma unroll
    for (int kk = 0; kk < 16; ++kk) {
      w1h_[kk] = *(const bf16x8*)(p1 + kk * 32);
      w1l_[kk] = *(const bf16x8*)(q1 + kk * 32);
    }
  }
  const float bias0 = beff[wrow], bias0t0 = db0[wrow], bias1 = b1[wrow];
  const float fcbv = (wid < 2) ? fcb[wid * 16 + lcol] : 0.f;
  unsigned* gflags = flags + gb * 64;
  __syncthreads();

  bf16x8 h1h_r[8], h1l_r[8];

  for (int t = 0; t < 512; ++t) {
    const int wp = t & 1, rp = 1 - wp;

    // ================= phase A : layer0 =================
    f32x4 a0, a1, a2, a3;
    if (t > 0) {   // issue h1(rp) staging
      const unsigned short* ph = h1h + (size_t)rp * 65536 + (size_t)(r0 + srow) * 256 + scol8;
      const unsigned short* pl = h1l + (size_t)rp * 65536 + (size_t)(r0 + srow) * 256 + scol8;
      a0 = ld16(ph); a1 = ld16(ph + 2048);
      a2 = ld16(pl); a3 = ld16(pl + 2048);
    }
    // overlap: Whh0 half on s_h0[rp] (staged during phase B of t-1 / prologue)
    f32x4 ahh = {0.f,0.f,0.f,0.f}, ahl = {0.f,0.f,0.f,0.f}, alh = {0.f,0.f,0.f,0.f};
    #pragma unroll
    for (int kk = 0; kk < 8; ++kk) {
      bf16x8 fh_ = LDSF(s_h0[rp][0], lcol, kk);
      bf16x8 fl_ = LDSF(s_h0[rp][1], lcol, kk);
      ahh = MFMA16(fh_, w0h_[kk + 8], ahh);
      ahl = MFMA16(fh_, w0l_[kk + 8], ahl);
      alh = MFMA16(fl_, w0h_[kk + 8], alh);
    }
    if (t > 0) {
      wait_vm0();
      *(f32x4*)(s_h1[0] + dA) = a0; *(f32x4*)(s_h1[0] + dB) = a1;
      *(f32x4*)(s_h1[1] + dA) = a2; *(f32x4*)(s_h1[1] + dB) = a3;
    }
    __syncthreads();
    #pragma unroll
    for (int kk = 0; kk < 8; ++kk) {   // h1 frags: used in A (Weff) and B (Whh1, pred)
      h1h_r[kk] = LDSF(s_h1[0], lcol, kk);
      h1l_r[kk] = LDSF(s_h1[1], lcol, kk);
    }
    if (t > 0) {   // Weff half (t==0: x=0, no contribution)
      #pragma unroll
      for (int kk = 0; kk < 8; ++kk) {
        ahh = MFMA16(h1h_r[kk], w0h_[kk], ahh);
        ahl = MFMA16(h1h_r[kk], w0l_[kk], ahl);
        alh = MFMA16(h1l_r[kk], w0h_[kk], alh);
      }
    }
    {
      f32x4 g = ahh + ahl + alh;
      float bb = (t == 0) ? bias0t0 : bias0;
      #pragma unroll
      for (int r = 0; r < 4; ++r) gA[wid][lrow * 4 + r][lcol] = g[r] + bb;
    }
    __syncthreads();
    {
      const int urow = tid >> 4, uu = tid & 15;
      float gi = gA[0][urow][uu], gf = gA[1][urow][uu];
      float gg = gA[2][urow][uu], go = gA[3][urow][uu];
      float c = sigf(gf) * cb[0][urow][uu] + sigf(gi) * tanhsafe(gg);
      cb[0][urow][uu] = c;
      float h = sigf(go) * tanhsafe(c);
      size_t off = (size_t)wp * 65536 + (size_t)(r0 + urow) * 256 + (u0 + uu);
      st_hpair(h, h0h + off, h0l + off);
    }
    flag_barrier(gflags, gc, (unsigned)(2 * t + 1));

    // ================= phase B : layer1 (+ pred(t-1)) =================
    f32x4 b0v, b1v, b2v, b3v;
    {   // issue h0'(wp) staging
      const unsigned short* ph = h0h + (size_t)wp * 65536 + (size_t)(r0 + srow) * 256 + scol8;
      const unsigned short* pl = h0l + (size_t)wp * 65536 + (size_t)(r0 + srow) * 256 + scol8;
      b0v = ld16(ph); b1v = ld16(ph + 2048);
      b2v = ld16(pl); b3v = ld16(pl + 2048);
    }
    // overlap: Whh1 half (h1 regs) + pred(t-1)
    f32x4 bhh = {0.f,0.f,0.f,0.f}, bhl = {0.f,0.f,0.f,0.f}, blh = {0.f,0.f,0.f,0.f};
    #pragma unroll
    for (int kk = 0; kk < 8; ++kk) {
      bhh = MFMA16(h1h_r[kk], w1h_[kk + 8], bhh);
      bhl = MFMA16(h1h_r[kk], w1l_[kk + 8], bhl);
      blh = MFMA16(h1l_r[kk], w1h_[kk + 8], blh);
    }
    f32x4 p0 = {0.f,0.f,0.f,0.f}, p1 = {0.f,0.f,0.f,0.f}, p2 = {0.f,0.f,0.f,0.f};
    if (t > 0 && wid < 2) {
      #pragma unroll
      for (int kk = 0; kk < 8; ++kk) {
        bf16x8 fh_ = LDSF(s_fcw[0], wid * 16 + lcol, kk);
        bf16x8 fl_ = LDSF(s_fcw[1], wid * 16 + lcol, kk);
        p0 = MFMA16(h1h_r[kk], fh_, p0);
        p1 = MFMA16(h1h_r[kk], fl_, p1);
        p2 = MFMA16(h1l_r[kk], fh_, p2);
      }
    }
    wait_vm0();
    if (t > 0 && wid < 2 && gc == 0) {
      // D[row=batch=lrow*4+j][col=fc-col=lcol]; pred(t-1) -> slot 512-t
      #pragma unroll
      for (int j = 0; j < 4; ++j)
        out[(size_t)(r0 + lrow * 4 + j) * 16384 + (size_t)(512 - t) * 32 + wid * 16 + lcol] =
            p0[j] + p1[j] + p2[j] + fcbv;
    }
    *(f32x4*)(s_h0[wp][0] + dA) = b0v; *(f32x4*)(s_h0[wp][0] + dB) = b1v;
    *(f32x4*)(s_h0[wp][1] + dA) = b2v; *(f32x4*)(s_h0[wp][1] + dB) = b3v;
    __syncthreads();
    {
      #pragma unroll
      for (int kk = 0; kk < 8; ++kk) {
        bf16x8 fh_ = LDSF(s_h0[wp][0], lcol, kk);
        bf16x8 fl_ = LDSF(s_h0[wp][1], lcol, kk);
        bhh = MFMA16(fh_, w1h_[kk], bhh);
        bhl = MFMA16(fh_, w1l_[kk], bhl);
        blh = MFMA16(fl_, w1h_[kk], blh);
      }
      f32x4 g = bhh + bhl + blh;
      #pragma unroll
      for (int r = 0; r < 4; ++r) gA[wid][lrow * 4 + r][lcol] = g[r] + bias1;
    }
    __syncthreads();
    {
      const int urow = tid >> 4, uu = tid & 15;
      float gi = gA[0][urow][uu], gf = gA[1][urow][uu];
      float gg = gA[2][urow][uu], go = gA[3][urow][uu];
      float c = sigf(gf) * cb[1][urow][uu] + sigf(gi) * tanhsafe(gg);
      cb[1][urow][uu] = c;
      float h = sigf(go) * tanhsafe(c);
      size_t off = (size_t)wp * 65536 + (size_t)(r0 + urow) * 256 + (u0 + uu);
      st_hpair(h, h1h + off, h1l + off);
    }
    flag_barrier(gflags, gc, (unsigned)(2 * t + 2));
  }

  // ---- tail: pred(511) from h1(par1) -> slot 0
  {
    const unsigned short* ph = h1h + 65536 + (size_t)(r0 + srow) * 256 + scol8;
    const unsigned short* pl = h1l + 65536 + (size_t)(r0 + srow) * 256 + scol8;
    f32x4 v0 = ld16(ph), v1 = ld16(ph + 2048);
    f32x4 v2 = ld16(pl), v3 = ld16(pl + 2048);
    wait_vm0();
    *(f32x4*)(s_h1[0] + dA) = v0; *(f32x4*)(s_h1[0] + dB) = v1;
    *(f32x4*)(s_h1[1] + dA) = v2; *(f32x4*)(s_h1[1] + dB) = v3;
  }
  __syncthreads();
  if (wid < 2) {
    f32x4 p0 = {0.f,0.f,0.f,0.f}, p1 = {0.f,0.f,0.f,0.f}, p2 = {0.f,0.f,0.f,0.f};
    #pragma unroll
    for (int kk = 0; kk < 8; ++kk) {
      bf16x8 ah = LDSF(s_h1[0], lcol, kk);
      bf16x8 al = LDSF(s_h1[1], lcol, kk);
      bf16x8 fh_ = LDSF(s_fcw[0], wid * 16 + lcol, kk);
      bf16x8 fl_ = LDSF(s_fcw[1], wid * 16 + lcol, kk);
      p0 = MFMA16(ah, fh_, p0);
      p1 = MFMA16(ah, fl_, p1);
      p2 = MFMA16(al, fh_, p2);
    }
    if (gc == 0) {
      #pragma unroll
      for (int j = 0; j < 4; ++j)
        out[(size_t)(r0 + lrow * 4 + j) * 16384 + wid * 16 + lcol] = p0[j] + p1[j] + p2[j] + fcbv;
    }
  }
}

// ---------------- launch ----------------
extern "C" void kernel_launch(void* const* d_in, const int* in_sizes, int n_in,
                              void* d_out, int out_size, void* d_ws, size_t ws_size,
                              hipStream_t stream) {
  (void)in_sizes; (void)n_in; (void)ws_size;
  const float* input = (const float*)d_in[0];
  const float* eWih0 = (const float*)d_in[1];
  const float* eWhh0 = (const float*)d_in[2];
  const float* eb0   = (const float*)d_in[3];
  const float* eWih1 = (const float*)d_in[4];
  const float* eWhh1 = (const float*)d_in[5];
  const float* eb1   = (const float*)d_in[6];
  const float* dWih0 = (const float*)d_in[7];
  const float* dWhh0 = (const float*)d_in[8];
  const float* db0   = (const float*)d_in[9];
  const float* dWih1 = (const float*)d_in[10];
  const float* dWhh1 = (const float*)d_in[11];
  const float* db1   = (const float*)d_in[12];
  const float* fcW   = (const float*)d_in[13];
  const float* fcb   = (const float*)d_in[14];

  char* ws = (char*)d_ws;
  unsigned short* h0h = (unsigned short*)(ws + OFF_H0H);
  unsigned short* h0l = (unsigned short*)(ws + OFF_H0L);
  unsigned short* h1h = (unsigned short*)(ws + OFF_H1H);
  unsigned short* h1l = (unsigned short*)(ws + OFF_H1L);
  float* cfin = (float*)(ws + OFF_CFIN);
  unsigned short* ew0h = (unsigned short*)(ws + OFF_EW0H);
  unsigned short* ew0l = (unsigned short*)(ws + OFF_EW0L);
  unsigned short* ew1h = (unsigned short*)(ws + OFF_EW1H);
  unsigned short* ew1l = (unsigned short*)(ws + OFF_EW1L);
  unsigned short* dw0h = (unsigned short*)(ws + OFF_DW0H);
  unsigned short* dw0l = (unsigned short*)(ws + OFF_DW0L);
  unsigned short* dw1h = (unsigned short*)(ws + OFF_DW1H);
  unsigned short* dw1l = (unsigned short*)(ws + OFF_DW1L);
  float* beff = (float*)(ws + OFF_BEFF);
  unsigned short* fcwh = (unsigned short*)(ws + OFF_FCWH);
  unsigned short* fcwl = (unsigned short*)(ws + OFF_FCWL);
  unsigned* eflg = (unsigned*)(ws + OFF_EFLG);
  unsigned* dflg = (unsigned*)(ws + OFF_DFLG);

  hipMemsetAsync(d_out, 0, (size_t)out_size * sizeof(float), stream);
  hipMemsetAsync(ws + OFF_H0H, 0, (size_t)4 * SZ_HBUF, stream);   // zero initial h state
  hipMemsetAsync(ws + OFF_EFLG, 0, 8192, stream);                 // barrier flags

  k_prep_cat<<<1024, 256, 0, stream>>>(1024, eWih0, 32,  eWhh0, 256, ew0h, ew0l);
  k_prep_cat<<<1024, 256, 0, stream>>>(1024, eWih1, 256, eWhh1, 256, ew1h, ew1l);
  k_prep_cat<<<1024, 256, 0, stream>>>(1024, dWih1, 256, dWhh1, 256, dw1h, dw1l);
  k_prep_cat<<<64, 256, 0, stream>>>(32, fcW, 256, fcW, 0, fcwh, fcwl);
  k_prep_dec0<<<1024, 256, 0, stream>>>(dWih0, dWhh0, fcW, dw0h, dw0l);
  k_prep_beff<<<4, 256, 0, stream>>>(dWih0, db0, fcb, beff);

  k_encoder<<<256, 256, 0, stream>>>(input, ew0h, ew0l, ew1h, ew1l, eb0, eb1,
                                     h0h, h0l, h1h, h1l, cfin, eflg);
  k_decoder<<<256, 256, 0, stream>>>(dw0h, dw0l, dw1h, dw1l, beff, db0, db1, fcb,
                                     fcwh, fcwl, h0h, h0l, h1h, h1l, cfin,
                                     (float*)d_out, dflg);
}